// Round 4
// baseline (1071.434 us; speedup 1.0000x reference)
//
#include <hip/hip_runtime.h>
#include <hip/hip_bf16.h>
#include <cstdint>

#define DEV_INLINE __device__ __forceinline__

// problem constants
constexpr int N0n = 100000, N1n = 25000, N2n = 6250;
constexpr int E0n = 800000, E1n = 200000, E2n = 50000;
constexpr int NT  = N0n + N1n + N2n;     // 131250 concatenated node space
constexpr int ET  = E0n + E1n + E2n;     // 1050000 concatenated edge space
constexpr int Bn  = 2;

// sanitize: legit values in this net are all |v| < 10; junk/NaN/Inf -> 0.
DEV_INLINE float sane(float v) { return (v == v && fabsf(v) < 1e4f) ? v : 0.f; }
DEV_INLINE float lrelu(float x) { return x > 0.f ? x : 0.01f * x; }

// ---------------- CSR build (3 graphs concatenated) ----------------

__global__ __launch_bounds__(256) void k_deg_count(const int* __restrict__ g0,
                                                   const int* __restrict__ g1,
                                                   const int* __restrict__ g2,
                                                   int* __restrict__ deg) {
    int e = blockIdx.x * 256 + threadIdx.x;
    int gd = -1;
    if (e < E0n)                gd = g0[E0n + e] % N0n;
    else if (e < E0n + E1n)     gd = N0n + (g1[E1n + (e - E0n)] % N1n);
    else if (e < ET)            gd = N0n + N1n + (g2[E2n + (e - E0n - E1n)] % N2n);
    if (gd >= 0 && gd < NT) atomicAdd(&deg[gd], 1);
}

constexpr int SCAN_CHUNK = 2048;
constexpr int NCHUNK = (NT + SCAN_CHUNK - 1) / SCAN_CHUNK;   // 65

__global__ __launch_bounds__(256) void k_scan1(const int* __restrict__ deg,
                                               int* __restrict__ out,
                                               int* __restrict__ partials) {
    __shared__ int sums[256];
    const int chunk = blockIdx.x, t = threadIdx.x;
    const int base = chunk * SCAN_CHUNK + t * 8;
    int v[8]; int s = 0;
#pragma unroll
    for (int i = 0; i < 8; i++) { int idx = base + i; v[i] = (idx < NT) ? deg[idx] : 0; s += v[i]; }
    int val = s;
    sums[t] = val; __syncthreads();
    for (int off = 1; off < 256; off <<= 1) {
        int y = (t >= off) ? sums[t - off] : 0;
        __syncthreads();
        val += y; sums[t] = val;
        __syncthreads();
    }
    const int excl = val - s;
    if (t == 255) partials[chunk] = val;
    int run = excl;
#pragma unroll
    for (int i = 0; i < 8; i++) { int idx = base + i; if (idx < NT) out[idx] = run; run += v[i]; }
}

__global__ void k_scan2(int* __restrict__ partials, int* __restrict__ offsets) {
    if (threadIdx.x == 0 && blockIdx.x == 0) {
        int run = 0;
        for (int i = 0; i < NCHUNK; i++) { int p = partials[i]; partials[i] = run; run += p; }
        offsets[NT] = run;   // == ET
    }
}

__global__ __launch_bounds__(256) void k_scan3(const int* __restrict__ partials,
                                               int* __restrict__ offsets) {
    int idx = blockIdx.x * 256 + threadIdx.x;
    if (idx < NT) offsets[idx] += partials[idx / SCAN_CHUNK];
}

__global__ __launch_bounds__(256) void k_csr_fill(const int* __restrict__ g0,
                                                  const int* __restrict__ g1,
                                                  const int* __restrict__ g2,
                                                  const int* __restrict__ offsets,
                                                  int* __restrict__ cursor,
                                                  int* __restrict__ csr) {
    int e = blockIdx.x * 256 + threadIdx.x;
    int src, gd;
    if (e < E0n)            { src = g0[e] % N0n;            gd = g0[E0n + e] % N0n; }
    else if (e < E0n + E1n) { int le = e - E0n;             src = g1[le] % N1n; gd = N0n + (g1[E1n + le] % N1n); }
    else if (e < ET)        { int le = e - E0n - E1n;       src = g2[le] % N2n; gd = N0n + N1n + (g2[E2n + le] % N2n); }
    else return;
    int pos = offsets[gd] + atomicAdd(&cursor[gd], 1);
    if (pos >= 0 && pos < ET) csr[pos] = src;   // local src id
}

// ---------------- latent MLP: z -> x0 [N2, B, 128] ----------------

__global__ __launch_bounds__(256) void k_latent(const float* __restrict__ z,
                                                const float* __restrict__ W1,
                                                const float* __restrict__ b1,
                                                const float* __restrict__ W2,
                                                const float* __restrict__ b2,
                                                float* __restrict__ x0) {
    __shared__ float col[64];
    const int t = threadIdx.x;
    const int b = t >> 7, l = t & 127;
    const float zv = sane(z[b * 128 + l]);
    float h1[64];
#pragma unroll
    for (int k = 0; k < 64; k++) h1[k] = lrelu(zv * sane(W1[k]) + sane(b1[k]));
    for (int nn = 0; nn < 8; nn++) {
        const int n = blockIdx.x * 8 + nn;
        if (n >= N2n) break;                 // uniform across block
        if (t < 64) col[t] = sane(W2[t * N2n + n]);
        __syncthreads();
        float s = sane(b2[n]);
#pragma unroll
        for (int k = 0; k < 64; k++) s += h1[k] * col[k];
        x0[((size_t)n * Bn + b) * 128 + l] = s;
        __syncthreads();
    }
}

// ---------------- dual GEMM: U = x(Wa-Wb)+b, V = x*Wb ----------------
// x: [Mrows, K] fp32 (rows = (node,b)); W: [2K, COUT] fp32.
// Output rows scattered via m_id into compact U/V arrays (row id = m_id[n] < nnz).

template <int K, int COUT>
__global__ __launch_bounds__(256) void k_gemm_uv(const float* __restrict__ x,
                                                 const float* __restrict__ W,
                                                 const float* __restrict__ bias,
                                                 const int* __restrict__ m_id,
                                                 float* __restrict__ U, float* __restrict__ V,
                                                 int Mrows) {
    constexpr int TM = 64, TN = 64, TK = 32;
    __shared__ float xs[TK][TM + 4];
    __shared__ float wd[TK][TN];
    __shared__ float wb[TK][TN];
    const int t = threadIdx.x;
    const int row0 = blockIdx.x * TM;
    const int col0 = blockIdx.y * TN;
    const int tr = (t & 15) * 4;
    const int tc = (t >> 4) * 4;
    const int lrow = t >> 2;            // x-load: row in tile
    const int lseg = (t & 3) * 8;       // x-load: k segment
    const int wrow = t >> 3;            // w-load: k row
    const int wseg = (t & 7) * 8;       // w-load: col segment
    float accU[4][4] = {}, accV[4][4] = {};

    for (int k0 = 0; k0 < K; k0 += TK) {
        __syncthreads();
        {   // x tile
            float4 a0 = {0, 0, 0, 0}, a1 = {0, 0, 0, 0};
            const int gr = row0 + lrow;
            if (gr < Mrows) {
                const float* p = x + (size_t)gr * K + k0 + lseg;
                a0 = ((const float4*)p)[0];
                a1 = ((const float4*)p)[1];
            }
            xs[lseg + 0][lrow] = sane(a0.x); xs[lseg + 1][lrow] = sane(a0.y);
            xs[lseg + 2][lrow] = sane(a0.z); xs[lseg + 3][lrow] = sane(a0.w);
            xs[lseg + 4][lrow] = sane(a1.x); xs[lseg + 5][lrow] = sane(a1.y);
            xs[lseg + 6][lrow] = sane(a1.z); xs[lseg + 7][lrow] = sane(a1.w);
        }
        {   // W tiles: rows [0,K) = Wa (multiplies x_i), rows [K,2K) = Wb (multiplies x_j - x_i)
            const float* wa = W + (size_t)(k0 + wrow) * COUT + col0 + wseg;
            const float* wbp = wa + (size_t)K * COUT;
            float fa[8], fb[8];
            *(float4*)&fa[0] = ((const float4*)wa)[0];
            *(float4*)&fa[4] = ((const float4*)wa)[1];
            *(float4*)&fb[0] = ((const float4*)wbp)[0];
            *(float4*)&fb[4] = ((const float4*)wbp)[1];
#pragma unroll
            for (int i = 0; i < 8; i++) {
                const float va = sane(fa[i]), vb = sane(fb[i]);
                wd[wrow][wseg + i] = va - vb;
                wb[wrow][wseg + i] = vb;
            }
        }
        __syncthreads();
#pragma unroll
        for (int kk = 0; kk < TK; ++kk) {
            const float4 a = *(const float4*)&xs[kk][tr];
            const float4 d = *(const float4*)&wd[kk][tc];
            const float4 e = *(const float4*)&wb[kk][tc];
            const float av[4] = {a.x, a.y, a.z, a.w};
            const float dv[4] = {d.x, d.y, d.z, d.w};
            const float ev[4] = {e.x, e.y, e.z, e.w};
#pragma unroll
            for (int i = 0; i < 4; i++)
#pragma unroll
                for (int j = 0; j < 4; j++) {
                    accU[i][j] += av[i] * dv[j];
                    accV[i][j] += av[i] * ev[j];
                }
        }
    }
    float bf4[4];
#pragma unroll
    for (int j = 0; j < 4; j++) bf4[j] = sane(bias[col0 + tc + j]);
#pragma unroll
    for (int i = 0; i < 4; i++) {
        const int r = row0 + tr + i;
        if (r < Mrows) {
            const int n = r >> 1, b = r & 1;
            const int nod = m_id ? m_id[n] : n;
            const size_t orow = ((size_t)nod * Bn + b) * COUT + col0 + tc;
            float4 uo = {accU[i][0] + bf4[0], accU[i][1] + bf4[1],
                         accU[i][2] + bf4[2], accU[i][3] + bf4[3]};
            float4 vo = {accV[i][0], accV[i][1], accV[i][2], accV[i][3]};
            *(float4*)(U + orow) = uo;
            *(float4*)(V + orow) = vo;
        }
    }
}

// ---------------- edge aggregation: out[i] = mean_j relu(u_i + v_j) ----------------
// C = Bn * Cout channels per node (batch folded; graph shared across batch).
// Sparse-unpool aware: U/V are stored compactly for rows < nnz.
//   i >= nnz  -> u = bias[channel]   (unpooled zero row: 0*W + b)
//   j >= nnz  -> v = 0               (unpooled zero src)

template <int C, bool SKIP>
__global__ __launch_bounds__(256) void k_edge_agg(const float* __restrict__ U,
                                                  const float* __restrict__ V,
                                                  const float* __restrict__ bias,
                                                  const int* __restrict__ offsets,
                                                  const int* __restrict__ csr,
                                                  int nbase, int nnodes, int nnz,
                                                  const float* __restrict__ skip,
                                                  float* __restrict__ out) {
    constexpr int COUTc = C / Bn;                 // per-batch channel count (pow2)
    constexpr int NPB = (C < 256) ? (256 / C) : 1;
    constexpr int CPT = (C + 255) / 256;
    const int t = threadIdx.x;
    const int sub = (C < 256) ? (t / C) : 0;
    const int c0  = (C < 256) ? (t % C) : t;
    const int i = blockIdx.x * NPB + sub;
    if (i >= nnodes) return;
    const int gi = nbase + i;
    int beg = offsets[gi], end = offsets[gi + 1];
    beg = max(0, min(beg, ET));
    end = max(beg, min(end, ET));
    end = min(end, beg + 1024);                   // defensive cap (max degree ~30)
    float u[CPT], acc[CPT];
#pragma unroll
    for (int q = 0; q < CPT; q++) {
        const int cc = c0 + q * 256;
        const float ub = sane(bias[cc & (COUTc - 1)]);
        u[q] = (i < nnz) ? sane(U[(size_t)i * C + cc]) : ub;
        acc[q] = 0.f;
    }
    for (int e = beg; e < end; ++e) {
        const int j = csr[e];
        const bool jn = ((unsigned)j < (unsigned)nnz);
        const float* vb = V + (size_t)j * C + c0;
#pragma unroll
        for (int q = 0; q < CPT; q++) {
            const float v = jn ? sane(vb[q * 256]) : 0.f;
            acc[q] += fmaxf(u[q] + v, 0.f);
        }
    }
    const int dg = end - beg;
    const float inv = 1.f / (float)(dg > 0 ? dg : 1);
#pragma unroll
    for (int q = 0; q < CPT; q++) {
        float r = acc[q] * inv;
        const size_t oi = (size_t)i * C + c0 + q * 256;
        if (SKIP) r = lrelu(r + sane(skip[oi]));
        out[oi] = r;
    }
}

// ---------------- decoder MLP + LayerNorm(3) ----------------

__global__ __launch_bounds__(256) void k_decoder(const float* __restrict__ xf,
                                                 const float* __restrict__ Wd1,
                                                 const float* __restrict__ bd1,
                                                 const float* __restrict__ Wd2,
                                                 const float* __restrict__ bd2,
                                                 const float* __restrict__ gamma,
                                                 const float* __restrict__ beta,
                                                 float* __restrict__ out) {
    __shared__ float w1[64 * 32];
    __shared__ float w2[32 * 3];
    __shared__ float sb1[32], sb2[3], sg[3], sbt[3];
    const int t = threadIdx.x;
    for (int i = t; i < 2048; i += 256) w1[i] = sane(Wd1[i]);
    if (t < 96) w2[t] = sane(Wd2[t]);
    if (t < 32) sb1[t] = sane(bd1[t]);
    if (t < 3) { sb2[t] = sane(bd2[t]); sg[t] = sane(gamma[t]); sbt[t] = sane(beta[t]); }
    __syncthreads();
    const int idx = blockIdx.x * 256 + t;
    if (idx >= Bn * N0n) return;
    const int b = idx / N0n, n = idx % N0n;
    const float4* xr4 = (const float4*)(xf + ((size_t)n * Bn + b) * 64);
    float xv[64];
#pragma unroll
    for (int q = 0; q < 16; q++) {
        float4 f = xr4[q];
        xv[4 * q] = sane(f.x); xv[4 * q + 1] = sane(f.y);
        xv[4 * q + 2] = sane(f.z); xv[4 * q + 3] = sane(f.w);
    }
    float h1[32];
#pragma unroll
    for (int c = 0; c < 32; c++) h1[c] = sb1[c];
    for (int k = 0; k < 64; k++) {
        const float4* wr = (const float4*)&w1[k * 32];
        const float xk = xv[k];
#pragma unroll
        for (int j = 0; j < 8; j++) {
            float4 wv = wr[j];
            h1[4 * j] += xk * wv.x; h1[4 * j + 1] += xk * wv.y;
            h1[4 * j + 2] += xk * wv.z; h1[4 * j + 3] += xk * wv.w;
        }
    }
#pragma unroll
    for (int c = 0; c < 32; c++) h1[c] = lrelu(h1[c]);
    float h2[3];
#pragma unroll
    for (int c2 = 0; c2 < 3; c2++) {
        float s = sb2[c2];
#pragma unroll
        for (int c = 0; c < 32; c++) s += h1[c] * w2[c * 3 + c2];
        h2[c2] = s;
    }
    const float mu = (h2[0] + h2[1] + h2[2]) * (1.f / 3.f);
    const float d0 = h2[0] - mu, d1 = h2[1] - mu, d2 = h2[2] - mu;
    const float var = (d0 * d0 + d1 * d1 + d2 * d2) * (1.f / 3.f);
    const float inv = rsqrtf(var + 1e-5f);
    const size_t ob = (size_t)b * N0n * 3 + (size_t)n * 3;
    out[ob + 0] = d0 * inv * sg[0] + sbt[0];
    out[ob + 1] = d1 * inv * sg[1] + sbt[1];
    out[ob + 2] = d2 * inv * sg[2] + sbt[2];
}

// ---------------- launch ----------------

extern "C" void kernel_launch(void* const* d_in, const int* in_sizes, int n_in,
                              void* d_out, int out_size, void* d_ws, size_t ws_size,
                              hipStream_t stream) {
    (void)in_sizes; (void)n_in; (void)out_size; (void)ws_size;
    // Reference is jnp.float32 throughout -> all float inputs are fp32, output fp32.
    const float* z   = (const float*)d_in[0];
    const int* g0    = (const int*)d_in[1];
    const int* g1    = (const int*)d_in[2];
    const int* g2    = (const int*)d_in[3];
    const int* m_id0 = (const int*)d_in[4];
    const int* m_id1 = (const int*)d_in[5];
    const float* W_up1 = (const float*)d_in[6];
    const float* b_up1 = (const float*)d_in[7];
    const float* W_up2 = (const float*)d_in[8];
    const float* b_up2 = (const float*)d_in[9];
    const float* Wb    = (const float*)d_in[10];
    const float* bb    = (const float*)d_in[11];
    const float* l0_W1 = (const float*)d_in[12];
    const float* l0_b1 = (const float*)d_in[13];
    const float* l0_W2 = (const float*)d_in[14];
    const float* l0_b2 = (const float*)d_in[15];
    const float* l0_Wsk = (const float*)d_in[16];
    const float* l0_bsk = (const float*)d_in[17];
    const float* l1_W1 = (const float*)d_in[18];
    const float* l1_b1 = (const float*)d_in[19];
    const float* l1_W2 = (const float*)d_in[20];
    const float* l1_b2 = (const float*)d_in[21];
    const float* l1_Wsk = (const float*)d_in[22];
    const float* l1_bsk = (const float*)d_in[23];
    const float* Wf    = (const float*)d_in[24];
    const float* bf_   = (const float*)d_in[25];
    const float* Wd1   = (const float*)d_in[26];
    const float* bd1   = (const float*)d_in[27];
    const float* Wd2   = (const float*)d_in[28];
    const float* bd2   = (const float*)d_in[29];
    const float* gamma = (const float*)d_in[30];
    const float* beta  = (const float*)d_in[31];

    char* p = (char*)d_ws;
    auto alloc = [&](size_t bytes) -> char* {
        char* r = p; p += (bytes + 255) & ~(size_t)255; return r;
    };
    int* offsets  = (int*)alloc((size_t)(NT + 1) * 4);
    int* partials = (int*)alloc((size_t)NCHUNK * 4);
    int* degcur   = (int*)alloc((size_t)2 * NT * 4);
    int* deg = degcur; int* cursor = degcur + NT;
    int* csr = (int*)alloc((size_t)ET * 4);

    // pooled slabs (fp32): A,B,C = 12.8M floats (51.2 MB) each, D = 3.2M floats.
    constexpr size_t SLOT = (size_t)N0n * Bn * 64;   // 12.8M floats
    float* A = (float*)alloc(SLOT * 4);
    float* B = (float*)alloc(SLOT * 4);
    float* C = (float*)alloc(SLOT * 4);
    float* D = (float*)alloc((size_t)N1n * Bn * 64 * 4);
    // total ws: ~5.8 MB CSR + 166.4 MB pool = ~172.2 MB

    // --- CSR build ---
    hipMemsetAsync(degcur, 0, (size_t)2 * NT * 4, stream);
    k_deg_count<<<(ET + 255) / 256, 256, 0, stream>>>(g0, g1, g2, deg);
    k_scan1<<<NCHUNK, 256, 0, stream>>>(deg, offsets, partials);
    k_scan2<<<1, 1, 0, stream>>>(partials, offsets);
    k_scan3<<<(NT + 255) / 256, 256, 0, stream>>>(partials, offsets);
    k_csr_fill<<<(ET + 255) / 256, 256, 0, stream>>>(g0, g1, g2, offsets, cursor, csr);

    const int nb2 = N0n + N1n;   // g2 node base
    const int nb1 = N0n;         // g1 node base
    constexpr size_t M1 = 1600000;   // 1.6M floats granularity within A

    // --- latent -> x0 [N2,B,128] @ A+0 ---
    float* x0 = A;
    k_latent<<<(N2n + 7) / 8, 256, 0, stream>>>(z, W_up1, b_up1, W_up2, b_up2, x0);

    // --- conv1: g2, Cin=128 -> 256 ; U@A[1.6M,4.8M) V@A[4.8M,8M) -> xc1 @ A[8M,11.2M) ---
    float* xc1 = A + 5 * M1;
    k_gemm_uv<128, 256><<<dim3(196, 4), 256, 0, stream>>>(x0, Wb, bb, nullptr,
                                                          A + M1, A + 3 * M1, N2n * Bn);
    k_edge_agg<512, false><<<N2n, 256, 0, stream>>>(A + M1, A + 3 * M1, bb, offsets, csr,
                                                    nb2, N2n, N2n, nullptr, xc1);

    // --- skip0: unpool->N1, g1, Cin=256 -> 128 ; sparse rows=N2n ; @ B[0,6.4M) ---
    float* skip0 = B;
    k_gemm_uv<256, 128><<<dim3(196, 2), 256, 0, stream>>>(xc1, l0_Wsk, l0_bsk, m_id1,
                                                          A, A + M1, N2n * Bn);
    k_edge_agg<256, false><<<N1n, 256, 0, stream>>>(A, A + M1, l0_bsk, offsets, csr,
                                                    nb1, N1n, N2n, nullptr, skip0);

    // --- l0_W1: xc1, g2, Cin=256 -> 64 ; U@A[3.2M,4M) V@A[4M,4.8M) -> t1 @ A[4.8M,5.6M) ---
    float* t1 = A + 3 * M1;
    k_gemm_uv<256, 64><<<dim3(196, 1), 256, 0, stream>>>(xc1, l0_W1, l0_b1, nullptr,
                                                         A + 2 * M1, A + 2 * M1 + 800000, N2n * Bn);
    k_edge_agg<128, false><<<(N2n + 1) / 2, 256, 0, stream>>>(A + 2 * M1, A + 2 * M1 + 800000,
                                                              l0_b1, offsets, csr,
                                                              nb2, N2n, N2n, nullptr, t1);

    // --- l0_W2: unpool(t1)->N1, g1, Cin=64 -> 128 ; sparse rows=N2n ; +skip0 -> x1 @ B[6.4M,12.8M) ---
    float* x1 = B + 4 * M1;
    k_gemm_uv<64, 128><<<dim3(196, 2), 256, 0, stream>>>(t1, l0_W2, l0_b2, m_id1,
                                                         A, A + M1, N2n * Bn);
    k_edge_agg<256, true><<<N1n, 256, 0, stream>>>(A, A + M1, l0_b2, offsets, csr,
                                                   nb1, N1n, N2n, skip0, x1);

    // --- skip1: unpool(x1)->N0, g0, Cin=128 -> 64 ; sparse rows=N1n ; @ C ---
    float* skip1 = C;
    k_gemm_uv<128, 64><<<dim3(782, 1), 256, 0, stream>>>(x1, l1_Wsk, l1_bsk, m_id0,
                                                         A, A + 2 * M1, N1n * Bn);
    k_edge_agg<128, false><<<(N0n + 1) / 2, 256, 0, stream>>>(A, A + 2 * M1, l1_bsk,
                                                              offsets, csr,
                                                              0, N0n, N1n, nullptr, skip1);

    // --- l1_W1: x1, g1, Cin=128 -> 64 ; U@A[6.4M,9.6M) V@A[9.6M,12.8M) -> t2 @ D ---
    float* t2 = D;
    k_gemm_uv<128, 64><<<dim3(782, 1), 256, 0, stream>>>(x1, l1_W1, l1_b1, nullptr,
                                                         A + 4 * M1, A + 6 * M1, N1n * Bn);
    k_edge_agg<128, false><<<(N1n + 1) / 2, 256, 0, stream>>>(A + 4 * M1, A + 6 * M1, l1_b1,
                                                              offsets, csr,
                                                              nb1, N1n, N1n, nullptr, t2);

    // --- l1_W2: unpool(t2)->N0, g0, Cin=64 -> 64 ; sparse rows=N1n ; +skip1 -> x2 @ B ---
    float* x2 = B;
    k_gemm_uv<64, 64><<<dim3(782, 1), 256, 0, stream>>>(t2, l1_W2, l1_b2, m_id0,
                                                        A, A + 2 * M1, N1n * Bn);
    k_edge_agg<128, true><<<(N0n + 1) / 2, 256, 0, stream>>>(A, A + 2 * M1, l1_b2,
                                                             offsets, csr,
                                                             0, N0n, N1n, skip1, x2);

    // --- final conv: x2, g0, Cin=64 -> 64 ; dense ; U@C V@A -> xf @ B ---
    float* xf = B;   // x2 dead after GEMM; agg reads U/V only
    k_gemm_uv<64, 64><<<dim3(3125, 1), 256, 0, stream>>>(x2, Wf, bf_, nullptr,
                                                         C, A, N0n * Bn);
    k_edge_agg<128, false><<<(N0n + 1) / 2, 256, 0, stream>>>(C, A, bf_, offsets, csr,
                                                              0, N0n, N0n, nullptr, xf);

    // --- decoder + LayerNorm ---
    k_decoder<<<(N0n * Bn + 255) / 256, 256, 0, stream>>>(xf, Wd1, bd1, Wd2, bd2, gamma, beta,
                                                          (float*)d_out);
}

// Round 5
// 720.483 us; speedup vs baseline: 1.4871x; 1.4871x over previous
//
#include <hip/hip_runtime.h>
#include <hip/hip_bf16.h>
#include <cstdint>

#define DEV_INLINE __device__ __forceinline__

// problem constants
constexpr int N0n = 100000, N1n = 25000, N2n = 6250;
constexpr int E0n = 800000, E1n = 200000, E2n = 50000;
constexpr int NT  = N0n + N1n + N2n;     // 131250 concatenated node space
constexpr int ET  = E0n + E1n + E2n;     // 1050000 concatenated edge space
constexpr int Bn  = 2;

DEV_INLINE float lrelu(float x) { return x > 0.f ? x : 0.01f * x; }

// ---------------- CSR build (3 graphs concatenated) ----------------

__global__ __launch_bounds__(256) void k_deg_count(const int* __restrict__ g0,
                                                   const int* __restrict__ g1,
                                                   const int* __restrict__ g2,
                                                   int* __restrict__ deg) {
    int e = blockIdx.x * 256 + threadIdx.x;
    int gd = -1;
    if (e < E0n)                gd = g0[E0n + e] % N0n;
    else if (e < E0n + E1n)     gd = N0n + (g1[E1n + (e - E0n)] % N1n);
    else if (e < ET)            gd = N0n + N1n + (g2[E2n + (e - E0n - E1n)] % N2n);
    if (gd >= 0 && gd < NT) atomicAdd(&deg[gd], 1);
}

constexpr int SCAN_CHUNK = 2048;
constexpr int NCHUNK = (NT + SCAN_CHUNK - 1) / SCAN_CHUNK;   // 65

__global__ __launch_bounds__(256) void k_scan1(const int* __restrict__ deg,
                                               int* __restrict__ out,
                                               int* __restrict__ partials) {
    __shared__ int sums[256];
    const int chunk = blockIdx.x, t = threadIdx.x;
    const int base = chunk * SCAN_CHUNK + t * 8;
    int v[8]; int s = 0;
#pragma unroll
    for (int i = 0; i < 8; i++) { int idx = base + i; v[i] = (idx < NT) ? deg[idx] : 0; s += v[i]; }
    int val = s;
    sums[t] = val; __syncthreads();
    for (int off = 1; off < 256; off <<= 1) {
        int y = (t >= off) ? sums[t - off] : 0;
        __syncthreads();
        val += y; sums[t] = val;
        __syncthreads();
    }
    const int excl = val - s;
    if (t == 255) partials[chunk] = val;
    int run = excl;
#pragma unroll
    for (int i = 0; i < 8; i++) { int idx = base + i; if (idx < NT) out[idx] = run; run += v[i]; }
}

__global__ void k_scan2(int* __restrict__ partials, int* __restrict__ offsets) {
    if (threadIdx.x == 0 && blockIdx.x == 0) {
        int run = 0;
        for (int i = 0; i < NCHUNK; i++) { int p = partials[i]; partials[i] = run; run += p; }
        offsets[NT] = run;   // == ET
    }
}

__global__ __launch_bounds__(256) void k_scan3(const int* __restrict__ partials,
                                               int* __restrict__ offsets) {
    int idx = blockIdx.x * 256 + threadIdx.x;
    if (idx < NT) offsets[idx] += partials[idx / SCAN_CHUNK];
}

__global__ __launch_bounds__(256) void k_csr_fill(const int* __restrict__ g0,
                                                  const int* __restrict__ g1,
                                                  const int* __restrict__ g2,
                                                  const int* __restrict__ offsets,
                                                  int* __restrict__ cursor,
                                                  int* __restrict__ csr) {
    int e = blockIdx.x * 256 + threadIdx.x;
    int src, gd;
    if (e < E0n)            { src = g0[e] % N0n;            gd = g0[E0n + e] % N0n; }
    else if (e < E0n + E1n) { int le = e - E0n;             src = g1[le] % N1n; gd = N0n + (g1[E1n + le] % N1n); }
    else if (e < ET)        { int le = e - E0n - E1n;       src = g2[le] % N2n; gd = N0n + N1n + (g2[E2n + le] % N2n); }
    else return;
    int pos = offsets[gd] + atomicAdd(&cursor[gd], 1);
    if (pos >= 0 && pos < ET) csr[pos] = src;   // local src id
}

// ---------------- latent MLP: z -> x0 [N2, B, 128] ----------------

__global__ __launch_bounds__(256) void k_latent(const float* __restrict__ z,
                                                const float* __restrict__ W1,
                                                const float* __restrict__ b1,
                                                const float* __restrict__ W2,
                                                const float* __restrict__ b2,
                                                float* __restrict__ x0) {
    __shared__ float col[64];
    const int t = threadIdx.x;
    const int b = t >> 7, l = t & 127;
    const float zv = z[b * 128 + l];
    float h1[64];
#pragma unroll
    for (int k = 0; k < 64; k++) h1[k] = lrelu(zv * W1[k] + b1[k]);
    for (int nn = 0; nn < 8; nn++) {
        const int n = blockIdx.x * 8 + nn;
        if (n >= N2n) break;                 // uniform across block
        if (t < 64) col[t] = W2[t * N2n + n];
        __syncthreads();
        float s = b2[n];
#pragma unroll
        for (int k = 0; k < 64; k++) s += h1[k] * col[k];
        x0[((size_t)n * Bn + b) * 128 + l] = s;
        __syncthreads();
    }
}

// ---------------- dual GEMM: U = x(Wa-Wb)+b, V = x*Wb ----------------
// x: [Mrows, K] fp32 (rows = (node,b)); W: [2K, COUT] fp32; compact row-major out.

template <int K, int COUT>
__global__ __launch_bounds__(256) void k_gemm_uv(const float* __restrict__ x,
                                                 const float* __restrict__ W,
                                                 const float* __restrict__ bias,
                                                 float* __restrict__ U, float* __restrict__ V,
                                                 int Mrows) {
    constexpr int TM = 64, TN = 64, TK = 32;
    __shared__ float xs[TK][TM + 4];
    __shared__ float wd[TK][TN];
    __shared__ float wb[TK][TN];
    const int t = threadIdx.x;
    const int row0 = blockIdx.x * TM;
    const int col0 = blockIdx.y * TN;
    const int tr = (t & 15) * 4;
    const int tc = (t >> 4) * 4;
    const int lrow = t >> 2;            // x-load: row in tile
    const int lseg = (t & 3) * 8;       // x-load: k segment
    const int wrow = t >> 3;            // w-load: k row
    const int wseg = (t & 7) * 8;       // w-load: col segment
    float accU[4][4] = {}, accV[4][4] = {};

    for (int k0 = 0; k0 < K; k0 += TK) {
        __syncthreads();
        {   // x tile
            float4 a0 = {0, 0, 0, 0}, a1 = {0, 0, 0, 0};
            const int gr = row0 + lrow;
            if (gr < Mrows) {
                const float* p = x + (size_t)gr * K + k0 + lseg;
                a0 = ((const float4*)p)[0];
                a1 = ((const float4*)p)[1];
            }
            xs[lseg + 0][lrow] = a0.x; xs[lseg + 1][lrow] = a0.y;
            xs[lseg + 2][lrow] = a0.z; xs[lseg + 3][lrow] = a0.w;
            xs[lseg + 4][lrow] = a1.x; xs[lseg + 5][lrow] = a1.y;
            xs[lseg + 6][lrow] = a1.z; xs[lseg + 7][lrow] = a1.w;
        }
        {   // W tiles: rows [0,K) = Wa (mult x_i), rows [K,2K) = Wb (mult x_j - x_i)
            const float* wa = W + (size_t)(k0 + wrow) * COUT + col0 + wseg;
            const float* wbp = wa + (size_t)K * COUT;
            float fa[8], fb[8];
            *(float4*)&fa[0] = ((const float4*)wa)[0];
            *(float4*)&fa[4] = ((const float4*)wa)[1];
            *(float4*)&fb[0] = ((const float4*)wbp)[0];
            *(float4*)&fb[4] = ((const float4*)wbp)[1];
#pragma unroll
            for (int i = 0; i < 8; i++) {
                wd[wrow][wseg + i] = fa[i] - fb[i];
                wb[wrow][wseg + i] = fb[i];
            }
        }
        __syncthreads();
#pragma unroll
        for (int kk = 0; kk < TK; ++kk) {
            const float4 a = *(const float4*)&xs[kk][tr];
            const float4 d = *(const float4*)&wd[kk][tc];
            const float4 e = *(const float4*)&wb[kk][tc];
            const float av[4] = {a.x, a.y, a.z, a.w};
            const float dv[4] = {d.x, d.y, d.z, d.w};
            const float ev[4] = {e.x, e.y, e.z, e.w};
#pragma unroll
            for (int i = 0; i < 4; i++)
#pragma unroll
                for (int j = 0; j < 4; j++) {
                    accU[i][j] += av[i] * dv[j];
                    accV[i][j] += av[i] * ev[j];
                }
        }
    }
    float bf4[4];
#pragma unroll
    for (int j = 0; j < 4; j++) bf4[j] = bias[col0 + tc + j];
#pragma unroll
    for (int i = 0; i < 4; i++) {
        const int r = row0 + tr + i;
        if (r < Mrows) {
            const size_t orow = (size_t)r * COUT + col0 + tc;
            float4 uo = {accU[i][0] + bf4[0], accU[i][1] + bf4[1],
                         accU[i][2] + bf4[2], accU[i][3] + bf4[3]};
            float4 vo = {accV[i][0], accV[i][1], accV[i][2], accV[i][3]};
            *(float4*)(U + orow) = uo;
            *(float4*)(V + orow) = vo;
        }
    }
}

// ---------------- single edge aggregation (dense): out[i] = mean_j relu(u_i + v_j) ----
// C = Bn * Cout channels per node. Edge loop unrolled x4 to pipeline gathers.

template <int C>
__global__ __launch_bounds__(256) void k_edge_agg(const float* __restrict__ U,
                                                  const float* __restrict__ V,
                                                  const int* __restrict__ offsets,
                                                  const int* __restrict__ csr,
                                                  int nbase, int nnodes,
                                                  float* __restrict__ out) {
    constexpr int NPB = (C < 256) ? (256 / C) : 1;
    constexpr int CPT = (C + 255) / 256;
    const int t = threadIdx.x;
    const int sub = (C < 256) ? (t / C) : 0;
    const int c0  = (C < 256) ? (t % C) : t;
    const int i = blockIdx.x * NPB + sub;
    if (i >= nnodes) return;
    const int gi = nbase + i;
    int beg = offsets[gi], end = offsets[gi + 1];
    beg = max(0, min(beg, ET));
    end = max(beg, min(end, ET));
    float u[CPT], acc[CPT];
#pragma unroll
    for (int q = 0; q < CPT; q++) { u[q] = U[(size_t)i * C + c0 + q * 256]; acc[q] = 0.f; }
    int e = beg;
    for (; e + 4 <= end; e += 4) {
        const int j0 = csr[e], j1 = csr[e + 1], j2 = csr[e + 2], j3 = csr[e + 3];
#pragma unroll
        for (int q = 0; q < CPT; q++) {
            const int cq = c0 + q * 256;
            const float v0 = V[(size_t)j0 * C + cq];
            const float v1 = V[(size_t)j1 * C + cq];
            const float v2 = V[(size_t)j2 * C + cq];
            const float v3 = V[(size_t)j3 * C + cq];
            acc[q] += fmaxf(u[q] + v0, 0.f) + fmaxf(u[q] + v1, 0.f)
                    + fmaxf(u[q] + v2, 0.f) + fmaxf(u[q] + v3, 0.f);
        }
    }
    for (; e < end; ++e) {
        const int j = csr[e];
#pragma unroll
        for (int q = 0; q < CPT; q++)
            acc[q] += fmaxf(u[q] + V[(size_t)j * C + c0 + q * 256], 0.f);
    }
    const int dg = end - beg;
    const float inv = 1.f / (float)(dg > 0 ? dg : 1);
#pragma unroll
    for (int q = 0; q < CPT; q++)
        out[(size_t)i * C + c0 + q * 256] = acc[q] * inv;
}

// ---------------- fused dual aggregation (Res_up layer output) ----------------
// out[i] = lrelu( mean_j relu(u2_i + v2_j) + mean_j relu(usk_i + vsk_j) )
// U/V stored compactly on [0,nnz); rows >= nnz are implicit: u = bias, v = 0.
// j >= nnz is wave-uniform -> V loads skipped entirely for those edges.

template <int C>
__global__ __launch_bounds__(256) void k_edge_agg_fused(const float* __restrict__ U2,
                                                        const float* __restrict__ V2,
                                                        const float* __restrict__ Usk,
                                                        const float* __restrict__ Vsk,
                                                        const float* __restrict__ b2,
                                                        const float* __restrict__ bsk,
                                                        const int* __restrict__ offsets,
                                                        const int* __restrict__ csr,
                                                        int nbase, int nnodes, int nnz,
                                                        float* __restrict__ out) {
    static_assert(C <= 256, "CPT==1 only");
    constexpr int COUTc = C / Bn;
    constexpr int NPB = 256 / C;
    const int t = threadIdx.x;
    const int sub = t / C;
    const int c0  = t % C;
    const int i = blockIdx.x * NPB + sub;
    if (i >= nnodes) return;
    const int gi = nbase + i;
    int beg = offsets[gi], end = offsets[gi + 1];
    beg = max(0, min(beg, ET));
    end = max(beg, min(end, ET));
    const int cb = c0 & (COUTc - 1);
    const float u2  = (i < nnz) ? U2[(size_t)i * C + c0]  : b2[cb];
    const float usk = (i < nnz) ? Usk[(size_t)i * C + c0] : bsk[cb];
    float a2 = 0.f, ask = 0.f;
    int e = beg;
    for (; e + 4 <= end; e += 4) {
        const int j0 = csr[e], j1 = csr[e + 1], j2 = csr[e + 2], j3 = csr[e + 3];
        float p0 = 0.f, p1 = 0.f, p2 = 0.f, p3 = 0.f;
        float q0 = 0.f, q1 = 0.f, q2 = 0.f, q3 = 0.f;
        if (j0 < nnz) { p0 = V2[(size_t)j0 * C + c0]; q0 = Vsk[(size_t)j0 * C + c0]; }
        if (j1 < nnz) { p1 = V2[(size_t)j1 * C + c0]; q1 = Vsk[(size_t)j1 * C + c0]; }
        if (j2 < nnz) { p2 = V2[(size_t)j2 * C + c0]; q2 = Vsk[(size_t)j2 * C + c0]; }
        if (j3 < nnz) { p3 = V2[(size_t)j3 * C + c0]; q3 = Vsk[(size_t)j3 * C + c0]; }
        a2  += fmaxf(u2 + p0, 0.f) + fmaxf(u2 + p1, 0.f)
             + fmaxf(u2 + p2, 0.f) + fmaxf(u2 + p3, 0.f);
        ask += fmaxf(usk + q0, 0.f) + fmaxf(usk + q1, 0.f)
             + fmaxf(usk + q2, 0.f) + fmaxf(usk + q3, 0.f);
    }
    for (; e < end; ++e) {
        const int j = csr[e];
        float pv = 0.f, qv = 0.f;
        if (j < nnz) { pv = V2[(size_t)j * C + c0]; qv = Vsk[(size_t)j * C + c0]; }
        a2  += fmaxf(u2 + pv, 0.f);
        ask += fmaxf(usk + qv, 0.f);
    }
    const int dg = end - beg;
    const float inv = 1.f / (float)(dg > 0 ? dg : 1);
    out[(size_t)i * C + c0] = lrelu((a2 + ask) * inv);
}

// ---------------- decoder MLP + LayerNorm(3) ----------------

__global__ __launch_bounds__(256) void k_decoder(const float* __restrict__ xf,
                                                 const float* __restrict__ Wd1,
                                                 const float* __restrict__ bd1,
                                                 const float* __restrict__ Wd2,
                                                 const float* __restrict__ bd2,
                                                 const float* __restrict__ gamma,
                                                 const float* __restrict__ beta,
                                                 float* __restrict__ out) {
    __shared__ float w1[64 * 32];
    __shared__ float w2[32 * 3];
    __shared__ float sb1[32], sb2[3], sg[3], sbt[3];
    const int t = threadIdx.x;
    for (int i = t; i < 2048; i += 256) w1[i] = Wd1[i];
    if (t < 96) w2[t] = Wd2[t];
    if (t < 32) sb1[t] = bd1[t];
    if (t < 3) { sb2[t] = bd2[t]; sg[t] = gamma[t]; sbt[t] = beta[t]; }
    __syncthreads();
    const int idx = blockIdx.x * 256 + t;
    if (idx >= Bn * N0n) return;
    const int b = idx / N0n, n = idx % N0n;
    const float4* xr4 = (const float4*)(xf + ((size_t)n * Bn + b) * 64);
    float xv[64];
#pragma unroll
    for (int q = 0; q < 16; q++) {
        float4 f = xr4[q];
        xv[4 * q] = f.x; xv[4 * q + 1] = f.y; xv[4 * q + 2] = f.z; xv[4 * q + 3] = f.w;
    }
    float h1[32];
#pragma unroll
    for (int c = 0; c < 32; c++) h1[c] = sb1[c];
    for (int k = 0; k < 64; k++) {
        const float4* wr = (const float4*)&w1[k * 32];
        const float xk = xv[k];
#pragma unroll
        for (int j = 0; j < 8; j++) {
            float4 wv = wr[j];
            h1[4 * j] += xk * wv.x; h1[4 * j + 1] += xk * wv.y;
            h1[4 * j + 2] += xk * wv.z; h1[4 * j + 3] += xk * wv.w;
        }
    }
#pragma unroll
    for (int c = 0; c < 32; c++) h1[c] = lrelu(h1[c]);
    float h2[3];
#pragma unroll
    for (int c2 = 0; c2 < 3; c2++) {
        float s = sb2[c2];
#pragma unroll
        for (int c = 0; c < 32; c++) s += h1[c] * w2[c * 3 + c2];
        h2[c2] = s;
    }
    const float mu = (h2[0] + h2[1] + h2[2]) * (1.f / 3.f);
    const float d0 = h2[0] - mu, d1 = h2[1] - mu, d2 = h2[2] - mu;
    const float var = (d0 * d0 + d1 * d1 + d2 * d2) * (1.f / 3.f);
    const float inv = rsqrtf(var + 1e-5f);
    const size_t ob = (size_t)b * N0n * 3 + (size_t)n * 3;
    out[ob + 0] = d0 * inv * sg[0] + sbt[0];
    out[ob + 1] = d1 * inv * sg[1] + sbt[1];
    out[ob + 2] = d2 * inv * sg[2] + sbt[2];
}

// ---------------- launch ----------------

extern "C" void kernel_launch(void* const* d_in, const int* in_sizes, int n_in,
                              void* d_out, int out_size, void* d_ws, size_t ws_size,
                              hipStream_t stream) {
    (void)in_sizes; (void)n_in; (void)out_size; (void)ws_size;
    const float* z   = (const float*)d_in[0];
    const int* g0    = (const int*)d_in[1];
    const int* g1    = (const int*)d_in[2];
    const int* g2    = (const int*)d_in[3];
    const float* W_up1 = (const float*)d_in[6];
    const float* b_up1 = (const float*)d_in[7];
    const float* W_up2 = (const float*)d_in[8];
    const float* b_up2 = (const float*)d_in[9];
    const float* Wb    = (const float*)d_in[10];
    const float* bb    = (const float*)d_in[11];
    const float* l0_W1 = (const float*)d_in[12];
    const float* l0_b1 = (const float*)d_in[13];
    const float* l0_W2 = (const float*)d_in[14];
    const float* l0_b2 = (const float*)d_in[15];
    const float* l0_Wsk = (const float*)d_in[16];
    const float* l0_bsk = (const float*)d_in[17];
    const float* l1_W1 = (const float*)d_in[18];
    const float* l1_b1 = (const float*)d_in[19];
    const float* l1_W2 = (const float*)d_in[20];
    const float* l1_b2 = (const float*)d_in[21];
    const float* l1_Wsk = (const float*)d_in[22];
    const float* l1_bsk = (const float*)d_in[23];
    const float* Wf    = (const float*)d_in[24];
    const float* bf_   = (const float*)d_in[25];
    const float* Wd1   = (const float*)d_in[26];
    const float* bd1   = (const float*)d_in[27];
    const float* Wd2   = (const float*)d_in[28];
    const float* bd2   = (const float*)d_in[29];
    const float* gamma = (const float*)d_in[30];
    const float* beta  = (const float*)d_in[31];

    char* p = (char*)d_ws;
    auto alloc = [&](size_t bytes) -> char* {
        char* r = p; p += (bytes + 255) & ~(size_t)255; return r;
    };
    int* offsets  = (int*)alloc((size_t)(NT + 1) * 4);
    int* partials = (int*)alloc((size_t)NCHUNK * 4);
    int* degcur   = (int*)alloc((size_t)2 * NT * 4);
    int* deg = degcur; int* cursor = degcur + NT;
    int* csr = (int*)alloc((size_t)ET * 4);

    // pooled slabs (fp32): A,B,C = 12.8M floats (51.2 MB) each, D = 3.2M floats.
    constexpr size_t SLOT = (size_t)N0n * Bn * 64;   // 12.8M floats
    constexpr size_t M1 = 1600000;                    // 1.6M-float granule
    float* A = (float*)alloc(SLOT * 4);
    float* B = (float*)alloc(SLOT * 4);
    float* C = (float*)alloc(SLOT * 4);
    float* D = (float*)alloc((size_t)N1n * Bn * 64 * 4);

    // --- CSR build ---
    hipMemsetAsync(degcur, 0, (size_t)2 * NT * 4, stream);
    k_deg_count<<<(ET + 255) / 256, 256, 0, stream>>>(g0, g1, g2, deg);
    k_scan1<<<NCHUNK, 256, 0, stream>>>(deg, offsets, partials);
    k_scan2<<<1, 1, 0, stream>>>(partials, offsets);
    k_scan3<<<(NT + 255) / 256, 256, 0, stream>>>(partials, offsets);
    k_csr_fill<<<(ET + 255) / 256, 256, 0, stream>>>(g0, g1, g2, offsets, cursor, csr);

    const int nb2 = N0n + N1n;   // g2 node base in offsets
    const int nb1 = N0n;         // g1 node base

    // --- latent -> x0 [N2,B,128] @ A[0,M1) ---
    float* x0 = A;
    k_latent<<<(N2n + 7) / 8, 256, 0, stream>>>(z, W_up1, b_up1, W_up2, b_up2, x0);

    // --- conv1 (g2, 128->256): U@A[M1,3M1) V@A[3M1,5M1) -> xc1 @ A[5M1,7M1) ---
    float* xc1 = A + 5 * M1;
    k_gemm_uv<128, 256><<<dim3(196, 4), 256, 0, stream>>>(x0, Wb, bb, A + M1, A + 3 * M1, N2n * Bn);
    k_edge_agg<512><<<N2n, 256, 0, stream>>>(A + M1, A + 3 * M1, offsets, csr, nb2, N2n, xc1);

    // --- l0_W1 (g2, 256->64): U@A[7M1,+.5) V@A[7.5M1,8M1) -> t1 @ A[0,M1) (x0 dead) ---
    float* t1 = A;
    k_gemm_uv<256, 64><<<dim3(196, 1), 256, 0, stream>>>(xc1, l0_W1, l0_b1,
                                                         A + 7 * M1, A + 7 * M1 + 800000, N2n * Bn);
    k_edge_agg<128><<<(N2n + 1) / 2, 256, 0, stream>>>(A + 7 * M1, A + 7 * M1 + 800000,
                                                       offsets, csr, nb2, N2n, t1);

    // --- l0_W2 GEMM (64->128): t1 -> U2@B[0,M1) V2@B[M1,2M1) ---
    k_gemm_uv<64, 128><<<dim3(196, 2), 256, 0, stream>>>(t1, l0_W2, l0_b2, B, B + M1, N2n * Bn);
    // --- skip0 GEMM (256->128): xc1 -> Usk@B[2M1,3M1) Vsk@B[3M1,4M1) ---
    k_gemm_uv<256, 128><<<dim3(196, 2), 256, 0, stream>>>(xc1, l0_Wsk, l0_bsk,
                                                          B + 2 * M1, B + 3 * M1, N2n * Bn);
    // --- fused layer0 agg (g1, C=256, nnz=N2n): -> x1 @ B[4M1,8M1) ---
    float* x1 = B + 4 * M1;
    k_edge_agg_fused<256><<<N1n, 256, 0, stream>>>(B, B + M1, B + 2 * M1, B + 3 * M1,
                                                   l0_b2, l0_bsk, offsets, csr,
                                                   nb1, N1n, N2n, x1);

    // --- l1_W1 (g1, 128->64): U@A[0,2M1) V@A[2M1,4M1) -> t2 @ D ---
    float* t2 = D;
    k_gemm_uv<128, 64><<<dim3(782, 1), 256, 0, stream>>>(x1, l1_W1, l1_b1, A, A + 2 * M1, N1n * Bn);
    k_edge_agg<128><<<(N1n + 1) / 2, 256, 0, stream>>>(A, A + 2 * M1, offsets, csr, nb1, N1n, t2);

    // --- l1_W2 GEMM (64->64): t2 -> U2@A[0,2M1) V2@A[2M1,4M1) ---
    k_gemm_uv<64, 64><<<dim3(782, 1), 256, 0, stream>>>(t2, l1_W2, l1_b2, A, A + 2 * M1, N1n * Bn);
    // --- skip1 GEMM (128->64): x1 -> Usk@A[4M1,6M1) Vsk@A[6M1,8M1) ---
    k_gemm_uv<128, 64><<<dim3(782, 1), 256, 0, stream>>>(x1, l1_Wsk, l1_bsk,
                                                         A + 4 * M1, A + 6 * M1, N1n * Bn);
    // --- fused layer1 agg (g0, C=128, nnz=N1n): -> x2 @ C ---
    float* x2 = C;
    k_edge_agg_fused<128><<<(N0n + 1) / 2, 256, 0, stream>>>(A, A + 2 * M1, A + 4 * M1, A + 6 * M1,
                                                             l1_b2, l1_bsk, offsets, csr,
                                                             0, N0n, N1n, x2);

    // --- final conv (g0, 64->64): x2 -> Uf@A (full) Vf@B (full, x1 dead) -> xf @ C ---
    float* xf = C;   // x2 dead after GEMM
    k_gemm_uv<64, 64><<<dim3(3125, 1), 256, 0, stream>>>(x2, Wf, bf_, A, B, N0n * Bn);
    k_edge_agg<128><<<(N0n + 1) / 2, 256, 0, stream>>>(A, B, offsets, csr, 0, N0n, xf);

    // --- decoder + LayerNorm ---
    k_decoder<<<(N0n * Bn + 255) / 256, 256, 0, stream>>>(xf, Wd1, bd1, Wd2, bd2, gamma, beta,
                                                          (float*)d_out);
}

// Round 6
// 669.060 us; speedup vs baseline: 1.6014x; 1.0769x over previous
//
#include <hip/hip_runtime.h>
#include <hip/hip_bf16.h>
#include <cstdint>

#define DEV_INLINE __device__ __forceinline__

// problem constants
constexpr int N0n = 100000, N1n = 25000, N2n = 6250;
constexpr int E0n = 800000, E1n = 200000, E2n = 50000;
constexpr int NT  = N0n + N1n + N2n;     // 131250 concatenated node space
constexpr int ET  = E0n + E1n + E2n;     // 1050000 concatenated edge space
constexpr int Bn  = 2;

DEV_INLINE float lrelu(float x) { return x > 0.f ? x : 0.01f * x; }

// ---------------- CSR build (3 graphs concatenated) ----------------

__global__ __launch_bounds__(256) void k_deg_count(const int* __restrict__ g0,
                                                   const int* __restrict__ g1,
                                                   const int* __restrict__ g2,
                                                   int* __restrict__ deg) {
    int e = blockIdx.x * 256 + threadIdx.x;
    int gd = -1;
    if (e < E0n)                gd = g0[E0n + e] % N0n;
    else if (e < E0n + E1n)     gd = N0n + (g1[E1n + (e - E0n)] % N1n);
    else if (e < ET)            gd = N0n + N1n + (g2[E2n + (e - E0n - E1n)] % N2n);
    if (gd >= 0 && gd < NT) atomicAdd(&deg[gd], 1);
}

constexpr int SCAN_CHUNK = 2048;
constexpr int NCHUNK = (NT + SCAN_CHUNK - 1) / SCAN_CHUNK;   // 65

__global__ __launch_bounds__(256) void k_scan1(const int* __restrict__ deg,
                                               int* __restrict__ out,
                                               int* __restrict__ partials) {
    __shared__ int sums[256];
    const int chunk = blockIdx.x, t = threadIdx.x;
    const int base = chunk * SCAN_CHUNK + t * 8;
    int v[8]; int s = 0;
#pragma unroll
    for (int i = 0; i < 8; i++) { int idx = base + i; v[i] = (idx < NT) ? deg[idx] : 0; s += v[i]; }
    int val = s;
    sums[t] = val; __syncthreads();
    for (int off = 1; off < 256; off <<= 1) {
        int y = (t >= off) ? sums[t - off] : 0;
        __syncthreads();
        val += y; sums[t] = val;
        __syncthreads();
    }
    const int excl = val - s;
    if (t == 255) partials[chunk] = val;
    int run = excl;
#pragma unroll
    for (int i = 0; i < 8; i++) { int idx = base + i; if (idx < NT) out[idx] = run; run += v[i]; }
}

__global__ void k_scan2(int* __restrict__ partials, int* __restrict__ offsets) {
    if (threadIdx.x == 0 && blockIdx.x == 0) {
        int run = 0;
        for (int i = 0; i < NCHUNK; i++) { int p = partials[i]; partials[i] = run; run += p; }
        offsets[NT] = run;   // == ET
    }
}

__global__ __launch_bounds__(256) void k_scan3(const int* __restrict__ partials,
                                               int* __restrict__ offsets) {
    int idx = blockIdx.x * 256 + threadIdx.x;
    if (idx < NT) offsets[idx] += partials[idx / SCAN_CHUNK];
}

__global__ __launch_bounds__(256) void k_csr_fill(const int* __restrict__ g0,
                                                  const int* __restrict__ g1,
                                                  const int* __restrict__ g2,
                                                  const int* __restrict__ offsets,
                                                  int* __restrict__ cursor,
                                                  int* __restrict__ csr) {
    int e = blockIdx.x * 256 + threadIdx.x;
    int src, gd;
    if (e < E0n)            { src = g0[e] % N0n;            gd = g0[E0n + e] % N0n; }
    else if (e < E0n + E1n) { int le = e - E0n;             src = g1[le] % N1n; gd = N0n + (g1[E1n + le] % N1n); }
    else if (e < ET)        { int le = e - E0n - E1n;       src = g2[le] % N2n; gd = N0n + N1n + (g2[E2n + le] % N2n); }
    else return;
    int pos = offsets[gd] + atomicAdd(&cursor[gd], 1);
    if (pos >= 0 && pos < ET) csr[pos] = src;   // local src id
}

// ---------------- latent MLP: z -> x0 [N2, B, 128] ----------------

__global__ __launch_bounds__(256) void k_latent(const float* __restrict__ z,
                                                const float* __restrict__ W1,
                                                const float* __restrict__ b1,
                                                const float* __restrict__ W2,
                                                const float* __restrict__ b2,
                                                float* __restrict__ x0) {
    __shared__ float col[64];
    const int t = threadIdx.x;
    const int b = t >> 7, l = t & 127;
    const float zv = z[b * 128 + l];
    float h1[64];
#pragma unroll
    for (int k = 0; k < 64; k++) h1[k] = lrelu(zv * W1[k] + b1[k]);
    for (int nn = 0; nn < 8; nn++) {
        const int n = blockIdx.x * 8 + nn;
        if (n >= N2n) break;                 // uniform across block
        if (t < 64) col[t] = W2[t * N2n + n];
        __syncthreads();
        float s = b2[n];
#pragma unroll
        for (int k = 0; k < 64; k++) s += h1[k] * col[k];
        x0[((size_t)n * Bn + b) * 128 + l] = s;
        __syncthreads();
    }
}

// ---------------- dual GEMM: U = x(Wa-Wb)+b, V = x*Wb ----------------
// 128x64 tile, 8x4 per thread. x: [Mrows,K] fp32; W: [2K,COUT] fp32; compact out.

template <int K, int COUT>
__global__ __launch_bounds__(256) void k_gemm_uv(const float* __restrict__ x,
                                                 const float* __restrict__ W,
                                                 const float* __restrict__ bias,
                                                 float* __restrict__ U, float* __restrict__ V,
                                                 int Mrows) {
    constexpr int TM = 128, TN = 64, TK = 32;
    __shared__ float xs[TK][TM + 4];
    __shared__ float wd[TK][TN];
    __shared__ float wb[TK][TN];
    const int t = threadIdx.x;
    const int row0 = blockIdx.x * TM;
    const int col0 = blockIdx.y * TN;
    const int tc = (t & 15) * 4;        // 16 col groups * 4
    const int tr = (t >> 4) * 8;        // 16 row groups * 8
    const int lrow = t >> 1;            // x-load: 128 rows, 2 thr/row
    const int lseg = (t & 1) * 16;      // x-load: 16 consecutive k
    const int wrow = t >> 3;            // w-load: 32 k rows
    const int wseg = (t & 7) * 8;       // w-load: 8 cols
    float accU[8][4] = {}, accV[8][4] = {};

    for (int k0 = 0; k0 < K; k0 += TK) {
        __syncthreads();
        {   // x tile: 4 float4 per thread, transposed store
            float4 a[4] = {{0,0,0,0},{0,0,0,0},{0,0,0,0},{0,0,0,0}};
            const int gr = row0 + lrow;
            if (gr < Mrows) {
                const float4* p = (const float4*)(x + (size_t)gr * K + k0 + lseg);
                a[0] = p[0]; a[1] = p[1]; a[2] = p[2]; a[3] = p[3];
            }
#pragma unroll
            for (int q = 0; q < 4; q++) {
                xs[lseg + 4 * q + 0][lrow] = a[q].x;
                xs[lseg + 4 * q + 1][lrow] = a[q].y;
                xs[lseg + 4 * q + 2][lrow] = a[q].z;
                xs[lseg + 4 * q + 3][lrow] = a[q].w;
            }
        }
        {   // W tiles: rows [0,K) = Wa (mult x_i), rows [K,2K) = Wb (mult x_j - x_i)
            const float* wa = W + (size_t)(k0 + wrow) * COUT + col0 + wseg;
            const float* wbp = wa + (size_t)K * COUT;
            float fa[8], fb[8];
            *(float4*)&fa[0] = ((const float4*)wa)[0];
            *(float4*)&fa[4] = ((const float4*)wa)[1];
            *(float4*)&fb[0] = ((const float4*)wbp)[0];
            *(float4*)&fb[4] = ((const float4*)wbp)[1];
#pragma unroll
            for (int i = 0; i < 8; i++) {
                wd[wrow][wseg + i] = fa[i] - fb[i];
                wb[wrow][wseg + i] = fb[i];
            }
        }
        __syncthreads();
#pragma unroll
        for (int kk = 0; kk < TK; ++kk) {
            const float4 a0 = *(const float4*)&xs[kk][tr];
            const float4 a1 = *(const float4*)&xs[kk][tr + 4];
            const float4 d = *(const float4*)&wd[kk][tc];
            const float4 e = *(const float4*)&wb[kk][tc];
            const float av[8] = {a0.x, a0.y, a0.z, a0.w, a1.x, a1.y, a1.z, a1.w};
            const float dv[4] = {d.x, d.y, d.z, d.w};
            const float ev[4] = {e.x, e.y, e.z, e.w};
#pragma unroll
            for (int i = 0; i < 8; i++)
#pragma unroll
                for (int j = 0; j < 4; j++) {
                    accU[i][j] += av[i] * dv[j];
                    accV[i][j] += av[i] * ev[j];
                }
        }
    }
    float bf4[4];
#pragma unroll
    for (int j = 0; j < 4; j++) bf4[j] = bias[col0 + tc + j];
#pragma unroll
    for (int i = 0; i < 8; i++) {
        const int r = row0 + tr + i;
        if (r < Mrows) {
            const size_t orow = (size_t)r * COUT + col0 + tc;
            float4 uo = {accU[i][0] + bf4[0], accU[i][1] + bf4[1],
                         accU[i][2] + bf4[2], accU[i][3] + bf4[3]};
            float4 vo = {accV[i][0], accV[i][1], accV[i][2], accV[i][3]};
            *(float4*)(U + orow) = uo;
            *(float4*)(V + orow) = vo;
        }
    }
}

// ---------------- dense edge agg (float4/lane): out[i] = mean_j relu(u_i + v_j) ----

DEV_INLINE void acc_relu4(float4& acc, const float4 u, const float4 v) {
    acc.x += fmaxf(u.x + v.x, 0.f);
    acc.y += fmaxf(u.y + v.y, 0.f);
    acc.z += fmaxf(u.z + v.z, 0.f);
    acc.w += fmaxf(u.w + v.w, 0.f);
}

template <int C>
__global__ __launch_bounds__(256) void k_edge_agg(const float* __restrict__ U,
                                                  const float* __restrict__ V,
                                                  const int* __restrict__ offsets,
                                                  const int* __restrict__ csr,
                                                  int nbase, int nnodes,
                                                  float* __restrict__ out) {
    constexpr int TPN = C / 4;
    constexpr int NPB = 256 / TPN;
    const int t = threadIdx.x;
    const int sub = t / TPN;
    const int c4 = (t % TPN) * 4;
    const int i = blockIdx.x * NPB + sub;
    if (i >= nnodes) return;
    const int gi = nbase + i;
    int beg = offsets[gi], end = offsets[gi + 1];
    beg = max(0, min(beg, ET));
    end = max(beg, min(end, ET));
    const float4 u = *(const float4*)&U[(size_t)i * C + c4];
    float4 acc = {0, 0, 0, 0};
    int e = beg;
    for (; e + 4 <= end; e += 4) {
        const int j0 = csr[e], j1 = csr[e + 1], j2 = csr[e + 2], j3 = csr[e + 3];
        const float4 v0 = *(const float4*)&V[(size_t)j0 * C + c4];
        const float4 v1 = *(const float4*)&V[(size_t)j1 * C + c4];
        const float4 v2 = *(const float4*)&V[(size_t)j2 * C + c4];
        const float4 v3 = *(const float4*)&V[(size_t)j3 * C + c4];
        acc_relu4(acc, u, v0); acc_relu4(acc, u, v1);
        acc_relu4(acc, u, v2); acc_relu4(acc, u, v3);
    }
    for (; e < end; ++e) {
        const float4 v = *(const float4*)&V[(size_t)csr[e] * C + c4];
        acc_relu4(acc, u, v);
    }
    const int dg = end - beg;
    const float inv = 1.f / (float)(dg > 0 ? dg : 1);
    float4 o = {acc.x * inv, acc.y * inv, acc.z * inv, acc.w * inv};
    *(float4*)&out[(size_t)i * C + c4] = o;
}

// ---------------- fused dual agg (Res_up output), float4/lane ----------------
// out[i] = lrelu( (sum_j relu(u2+v2_j) + sum_j relu(usk+vsk_j)) / deg )
// compact U/V on [0,nnz); i>=nnz -> u=bias; j>=nnz -> v=0 (wave-uniform skip).

template <int C>
__global__ __launch_bounds__(256) void k_edge_agg_fused(const float* __restrict__ U2,
                                                        const float* __restrict__ V2,
                                                        const float* __restrict__ Usk,
                                                        const float* __restrict__ Vsk,
                                                        const float* __restrict__ b2,
                                                        const float* __restrict__ bsk,
                                                        const int* __restrict__ offsets,
                                                        const int* __restrict__ csr,
                                                        int nbase, int nnodes, int nnz,
                                                        float* __restrict__ out) {
    constexpr int COUTc = C / Bn;
    constexpr int TPN = C / 4;
    constexpr int NPB = 256 / TPN;
    const int t = threadIdx.x;
    const int sub = t / TPN;
    const int c4 = (t % TPN) * 4;
    const int i = blockIdx.x * NPB + sub;
    if (i >= nnodes) return;
    const int gi = nbase + i;
    int beg = offsets[gi], end = offsets[gi + 1];
    beg = max(0, min(beg, ET));
    end = max(beg, min(end, ET));
    const int cb = c4 & (COUTc - 1);
    const float4 u2  = (i < nnz) ? *(const float4*)&U2[(size_t)i * C + c4]
                                 : *(const float4*)&b2[cb];
    const float4 usk = (i < nnz) ? *(const float4*)&Usk[(size_t)i * C + c4]
                                 : *(const float4*)&bsk[cb];
    float4 a2 = {0, 0, 0, 0}, ask = {0, 0, 0, 0};
    const float4 z4 = {0, 0, 0, 0};
    int e = beg;
    for (; e + 4 <= end; e += 4) {
        const int j0 = csr[e], j1 = csr[e + 1], j2 = csr[e + 2], j3 = csr[e + 3];
        float4 p0 = z4, p1 = z4, p2 = z4, p3 = z4;
        float4 q0 = z4, q1 = z4, q2 = z4, q3 = z4;
        if (j0 < nnz) { p0 = *(const float4*)&V2[(size_t)j0 * C + c4]; q0 = *(const float4*)&Vsk[(size_t)j0 * C + c4]; }
        if (j1 < nnz) { p1 = *(const float4*)&V2[(size_t)j1 * C + c4]; q1 = *(const float4*)&Vsk[(size_t)j1 * C + c4]; }
        if (j2 < nnz) { p2 = *(const float4*)&V2[(size_t)j2 * C + c4]; q2 = *(const float4*)&Vsk[(size_t)j2 * C + c4]; }
        if (j3 < nnz) { p3 = *(const float4*)&V2[(size_t)j3 * C + c4]; q3 = *(const float4*)&Vsk[(size_t)j3 * C + c4]; }
        acc_relu4(a2, u2, p0); acc_relu4(a2, u2, p1); acc_relu4(a2, u2, p2); acc_relu4(a2, u2, p3);
        acc_relu4(ask, usk, q0); acc_relu4(ask, usk, q1); acc_relu4(ask, usk, q2); acc_relu4(ask, usk, q3);
    }
    for (; e < end; ++e) {
        const int j = csr[e];
        float4 pv = z4, qv = z4;
        if (j < nnz) { pv = *(const float4*)&V2[(size_t)j * C + c4]; qv = *(const float4*)&Vsk[(size_t)j * C + c4]; }
        acc_relu4(a2, u2, pv); acc_relu4(ask, usk, qv);
    }
    const int dg = end - beg;
    const float inv = 1.f / (float)(dg > 0 ? dg : 1);
    float4 o = {lrelu((a2.x + ask.x) * inv), lrelu((a2.y + ask.y) * inv),
                lrelu((a2.z + ask.z) * inv), lrelu((a2.w + ask.w) * inv)};
    *(float4*)&out[(size_t)i * C + c4] = o;
}

// ---------------- fused final agg + decoder MLP + LayerNorm(3) ----------------
// Dense agg (C=128, g0) staged in LDS, then 16 rows x 16 threads matvec + LN.

__global__ __launch_bounds__(256) void k_agg_dec(const float* __restrict__ U,
                                                 const float* __restrict__ V,
                                                 const int* __restrict__ offsets,
                                                 const int* __restrict__ csr,
                                                 const float* __restrict__ Wd1,
                                                 const float* __restrict__ bd1,
                                                 const float* __restrict__ Wd2,
                                                 const float* __restrict__ bd2,
                                                 const float* __restrict__ gamma,
                                                 const float* __restrict__ beta,
                                                 float* __restrict__ out) {
    constexpr int C = 128;
    __shared__ float w1[2048];          // Wd1 [64,32]
    __shared__ float w2[96];            // Wd2 [32,3]
    __shared__ float sb1[32], sb2[3], sg[3], sbt[3];
    __shared__ float xs[16 * 66];       // 16 (n,b) rows of 64, stride 66 (bank spread)
    __shared__ float hs[16][33];        // h1 per row
    const int t = threadIdx.x;
    for (int i = t; i < 2048; i += 256) w1[i] = Wd1[i];
    if (t < 96) w2[t] = Wd2[t];
    if (t < 32) sb1[t] = bd1[t];
    if (t < 3) { sb2[t] = bd2[t]; sg[t] = gamma[t]; sbt[t] = beta[t]; }

    // --- agg phase: 8 nodes/block, 32 thr/node, float4/lane ---
    const int sub = t >> 5;
    const int c4 = (t & 31) * 4;        // channel = b*64 + k
    const int i0 = blockIdx.x * 8 + sub;
    float4 r = {0, 0, 0, 0};
    if (i0 < N0n) {
        int beg = offsets[i0], end = offsets[i0 + 1];
        beg = max(0, min(beg, ET));
        end = max(beg, min(end, ET));
        const float4 u = *(const float4*)&U[(size_t)i0 * C + c4];
        float4 acc = {0, 0, 0, 0};
        int e = beg;
        for (; e + 4 <= end; e += 4) {
            const int j0 = csr[e], j1 = csr[e + 1], j2 = csr[e + 2], j3 = csr[e + 3];
            const float4 v0 = *(const float4*)&V[(size_t)j0 * C + c4];
            const float4 v1 = *(const float4*)&V[(size_t)j1 * C + c4];
            const float4 v2 = *(const float4*)&V[(size_t)j2 * C + c4];
            const float4 v3 = *(const float4*)&V[(size_t)j3 * C + c4];
            acc_relu4(acc, u, v0); acc_relu4(acc, u, v1);
            acc_relu4(acc, u, v2); acc_relu4(acc, u, v3);
        }
        for (; e < end; ++e) {
            const float4 v = *(const float4*)&V[(size_t)csr[e] * C + c4];
            acc_relu4(acc, u, v);
        }
        const int dg = end - beg;
        const float inv = 1.f / (float)(dg > 0 ? dg : 1);
        r = {acc.x * inv, acc.y * inv, acc.z * inv, acc.w * inv};
    }
    // stage into LDS: row = sub*2 + b, col = k
    {
        const int rrow = sub * 2 + (c4 >> 6);
        const int rk = c4 & 63;
        float* xp = &xs[rrow * 66 + rk];
        xp[0] = r.x; xp[1] = r.y; xp[2] = r.z; xp[3] = r.w;
    }
    __syncthreads();

    // --- decoder phase: 16 rows x 16 threads; thread computes h1[l16], h1[l16+16] ---
    const int drow = t >> 4;
    const int l16 = t & 15;
    float h1a = sb1[l16], h1b = sb1[l16 + 16];
    const float* xrow = &xs[drow * 66];
#pragma unroll 8
    for (int k = 0; k < 64; k++) {
        const float xk = xrow[k];
        h1a += xk * w1[k * 32 + l16];
        h1b += xk * w1[k * 32 + l16 + 16];
    }
    hs[drow][l16] = lrelu(h1a);
    hs[drow][l16 + 16] = lrelu(h1b);
    __syncthreads();

    // --- h2 + LN: one thread per row ---
    if (t < 16) {
        const int node = t >> 1, b = t & 1;
        const int n = blockIdx.x * 8 + node;
        if (n < N0n) {
            float h2[3];
#pragma unroll
            for (int j = 0; j < 3; j++) {
                float s = sb2[j];
#pragma unroll
                for (int c = 0; c < 32; c++) s += hs[t][c] * w2[c * 3 + j];
                h2[j] = s;
            }
            const float mu = (h2[0] + h2[1] + h2[2]) * (1.f / 3.f);
            const float d0 = h2[0] - mu, d1 = h2[1] - mu, d2 = h2[2] - mu;
            const float var = (d0 * d0 + d1 * d1 + d2 * d2) * (1.f / 3.f);
            const float inv = rsqrtf(var + 1e-5f);
            const size_t ob = (size_t)b * N0n * 3 + (size_t)n * 3;
            out[ob + 0] = d0 * inv * sg[0] + sbt[0];
            out[ob + 1] = d1 * inv * sg[1] + sbt[1];
            out[ob + 2] = d2 * inv * sg[2] + sbt[2];
        }
    }
}

// ---------------- launch ----------------

extern "C" void kernel_launch(void* const* d_in, const int* in_sizes, int n_in,
                              void* d_out, int out_size, void* d_ws, size_t ws_size,
                              hipStream_t stream) {
    (void)in_sizes; (void)n_in; (void)out_size; (void)ws_size;
    const float* z   = (const float*)d_in[0];
    const int* g0    = (const int*)d_in[1];
    const int* g1    = (const int*)d_in[2];
    const int* g2    = (const int*)d_in[3];
    const float* W_up1 = (const float*)d_in[6];
    const float* b_up1 = (const float*)d_in[7];
    const float* W_up2 = (const float*)d_in[8];
    const float* b_up2 = (const float*)d_in[9];
    const float* Wb    = (const float*)d_in[10];
    const float* bb    = (const float*)d_in[11];
    const float* l0_W1 = (const float*)d_in[12];
    const float* l0_b1 = (const float*)d_in[13];
    const float* l0_W2 = (const float*)d_in[14];
    const float* l0_b2 = (const float*)d_in[15];
    const float* l0_Wsk = (const float*)d_in[16];
    const float* l0_bsk = (const float*)d_in[17];
    const float* l1_W1 = (const float*)d_in[18];
    const float* l1_b1 = (const float*)d_in[19];
    const float* l1_W2 = (const float*)d_in[20];
    const float* l1_b2 = (const float*)d_in[21];
    const float* l1_Wsk = (const float*)d_in[22];
    const float* l1_bsk = (const float*)d_in[23];
    const float* Wf    = (const float*)d_in[24];
    const float* bf_   = (const float*)d_in[25];
    const float* Wd1   = (const float*)d_in[26];
    const float* bd1   = (const float*)d_in[27];
    const float* Wd2   = (const float*)d_in[28];
    const float* bd2   = (const float*)d_in[29];
    const float* gamma = (const float*)d_in[30];
    const float* beta  = (const float*)d_in[31];

    char* p = (char*)d_ws;
    auto alloc = [&](size_t bytes) -> char* {
        char* r = p; p += (bytes + 255) & ~(size_t)255; return r;
    };
    int* offsets  = (int*)alloc((size_t)(NT + 1) * 4);
    int* partials = (int*)alloc((size_t)NCHUNK * 4);
    int* degcur   = (int*)alloc((size_t)2 * NT * 4);
    int* deg = degcur; int* cursor = degcur + NT;
    int* csr = (int*)alloc((size_t)ET * 4);

    // pooled slabs (fp32): A,B,C = 12.8M floats (51.2 MB) each, D = 3.2M floats.
    constexpr size_t SLOT = (size_t)N0n * Bn * 64;   // 12.8M floats
    constexpr size_t M1 = 1600000;                    // 1.6M-float granule
    float* A = (float*)alloc(SLOT * 4);
    float* B = (float*)alloc(SLOT * 4);
    float* C = (float*)alloc(SLOT * 4);
    float* D = (float*)alloc((size_t)N1n * Bn * 64 * 4);

    // --- CSR build ---
    hipMemsetAsync(degcur, 0, (size_t)2 * NT * 4, stream);
    k_deg_count<<<(ET + 255) / 256, 256, 0, stream>>>(g0, g1, g2, deg);
    k_scan1<<<NCHUNK, 256, 0, stream>>>(deg, offsets, partials);
    k_scan2<<<1, 1, 0, stream>>>(partials, offsets);
    k_scan3<<<(NT + 255) / 256, 256, 0, stream>>>(partials, offsets);
    k_csr_fill<<<(ET + 255) / 256, 256, 0, stream>>>(g0, g1, g2, offsets, cursor, csr);

    const int nb2 = N0n + N1n;   // g2 node base in offsets
    const int nb1 = N0n;         // g1 node base

    // --- latent -> x0 [N2,B,128] @ A[0,M1) ---
    float* x0 = A;
    k_latent<<<(N2n + 7) / 8, 256, 0, stream>>>(z, W_up1, b_up1, W_up2, b_up2, x0);

    // --- conv1 (g2, 128->256): U@A[M1,3M1) V@A[3M1,5M1) -> xc1 @ A[5M1,7M1) ---
    float* xc1 = A + 5 * M1;
    k_gemm_uv<128, 256><<<dim3(98, 4), 256, 0, stream>>>(x0, Wb, bb, A + M1, A + 3 * M1, N2n * Bn);
    k_edge_agg<512><<<(N2n + 1) / 2, 256, 0, stream>>>(A + M1, A + 3 * M1, offsets, csr, nb2, N2n, xc1);

    // --- l0_W1 (g2, 256->64): U@A[7M1,+.5) V@A[7.5M1,8M1) -> t1 @ A[0,M1) (x0 dead) ---
    float* t1 = A;
    k_gemm_uv<256, 64><<<dim3(98, 1), 256, 0, stream>>>(xc1, l0_W1, l0_b1,
                                                        A + 7 * M1, A + 7 * M1 + 800000, N2n * Bn);
    k_edge_agg<128><<<(N2n + 7) / 8, 256, 0, stream>>>(A + 7 * M1, A + 7 * M1 + 800000,
                                                       offsets, csr, nb2, N2n, t1);

    // --- l0_W2 GEMM (64->128): t1 -> U2@B[0,M1) V2@B[M1,2M1) ---
    k_gemm_uv<64, 128><<<dim3(98, 2), 256, 0, stream>>>(t1, l0_W2, l0_b2, B, B + M1, N2n * Bn);
    // --- skip0 GEMM (256->128): xc1 -> Usk@B[2M1,3M1) Vsk@B[3M1,4M1) ---
    k_gemm_uv<256, 128><<<dim3(98, 2), 256, 0, stream>>>(xc1, l0_Wsk, l0_bsk,
                                                         B + 2 * M1, B + 3 * M1, N2n * Bn);
    // --- fused layer0 agg (g1, C=256, nnz=N2n): -> x1 @ B[4M1,8M1) ---
    float* x1 = B + 4 * M1;
    k_edge_agg_fused<256><<<(N1n + 3) / 4, 256, 0, stream>>>(B, B + M1, B + 2 * M1, B + 3 * M1,
                                                             l0_b2, l0_bsk, offsets, csr,
                                                             nb1, N1n, N2n, x1);

    // --- l1_W1 (g1, 128->64): U@A[0,2M1) V@A[2M1,4M1) -> t2 @ D ---
    float* t2 = D;
    k_gemm_uv<128, 64><<<dim3(391, 1), 256, 0, stream>>>(x1, l1_W1, l1_b1, A, A + 2 * M1, N1n * Bn);
    k_edge_agg<128><<<(N1n + 7) / 8, 256, 0, stream>>>(A, A + 2 * M1, offsets, csr, nb1, N1n, t2);

    // --- l1_W2 GEMM (64->64): t2 -> U2@A[0,2M1) V2@A[2M1,4M1) ---
    k_gemm_uv<64, 64><<<dim3(391, 1), 256, 0, stream>>>(t2, l1_W2, l1_b2, A, A + 2 * M1, N1n * Bn);
    // --- skip1 GEMM (128->64): x1 -> Usk@A[4M1,6M1) Vsk@A[6M1,8M1) ---
    k_gemm_uv<128, 64><<<dim3(391, 1), 256, 0, stream>>>(x1, l1_Wsk, l1_bsk,
                                                         A + 4 * M1, A + 6 * M1, N1n * Bn);
    // --- fused layer1 agg (g0, C=128, nnz=N1n): -> x2 @ C ---
    float* x2 = C;
    k_edge_agg_fused<128><<<(N0n + 7) / 8, 256, 0, stream>>>(A, A + 2 * M1, A + 4 * M1, A + 6 * M1,
                                                             l1_b2, l1_bsk, offsets, csr,
                                                             0, N0n, N1n, x2);

    // --- final conv (g0, 64->64): x2 -> Uf@A (full) Vf@B (full, x1 dead) ---
    k_gemm_uv<64, 64><<<dim3(1563, 1), 256, 0, stream>>>(x2, Wf, bf_, A, B, N0n * Bn);
    // --- fused final agg + decoder + LN -> d_out ---
    k_agg_dec<<<(N0n + 7) / 8, 256, 0, stream>>>(A, B, offsets, csr,
                                                 Wd1, bd1, Wd2, bd2, gamma, beta,
                                                 (float*)d_out);
}